// Round 1
// 439.535 us; speedup vs baseline: 1.0730x; 1.0730x over previous
//
#include <hip/hip_runtime.h>
#include <hip/hip_bf16.h>

#define NNODES 50000
#define NEDGES 800000
#define DIM 128
#define NH 8
#define HID 512
#define NB 196               // scan blocks: ceil(50000/256)

typedef unsigned short ushort_t;
typedef unsigned int uint_t;
typedef __attribute__((ext_vector_type(8))) short bf16x8;
typedef __attribute__((ext_vector_type(4))) float f32x4;

// ---------------------------------------------------------------------------
// all three weight matrices in one dispatch (16384 + 262144 + 65536 = 344064)
__global__ __launch_bounds__(256) void convert_weights_kernel(
    const float* __restrict__ fc_w, const float* __restrict__ w1,
    const float* __restrict__ w2,
    ushort_t* __restrict__ fc_wb, ushort_t* __restrict__ w1b,
    ushort_t* __restrict__ w2b)
{
    int i = blockIdx.x * 256 + threadIdx.x;
    if (i < 16384)
        ((__hip_bfloat16*)fc_wb)[i] = __float2bfloat16(fc_w[i]);
    else if (i < 278528)
        ((__hip_bfloat16*)w1b)[i - 16384] = __float2bfloat16(w1[i - 16384]);
    else if (i < 344064)
        ((__hip_bfloat16*)w2b)[i - 278528] = __float2bfloat16(w2[i - 278528]);
}

// ---------------------------------------------------------------------------
// MFMA NT GEMM (verified r9): C = act(A@B^T + bias). BK=32, 3 blocks/CU.
// ---------------------------------------------------------------------------
template<int AF32, int OUTF32, int ACT>
__global__ __launch_bounds__(256, 3) void gemm_mfma(
    const void* A, int lda,
    const ushort_t* __restrict__ B, int ldb,
    const float* __restrict__ bias,
    void* C, int ldc, int row0,
    int M, int K)
{
    constexpr int BM = 128, BN = 128, BK = 32, PAD = 8;
    __shared__ ushort_t As[BM][BK + PAD];
    __shared__ ushort_t Bs[BN][BK + PAD];

    const int t    = threadIdx.x;
    const int bm   = blockIdx.y * BM;
    const int bn   = blockIdx.x * BN;
    const int wid  = t >> 6, lane = t & 63;
    const int wrow = wid >> 1, wcol = wid & 1;
    const int qd   = lane >> 4, l16 = lane & 15;

    f32x4 acc[4][4];
#pragma unroll
    for (int i = 0; i < 4; ++i)
#pragma unroll
        for (int j = 0; j < 4; ++j) acc[i][j] = (f32x4){0.f, 0.f, 0.f, 0.f};

    for (int k0 = 0; k0 < K; k0 += BK) {
#pragma unroll
        for (int i = 0; i < 2; ++i) {
            int v = t + i * 256;
            int r = v >> 2, c8 = (v & 3) * 8;
            int gr = bm + r;
            if (AF32) {
                float4 f0 = make_float4(0.f, 0.f, 0.f, 0.f), f1 = f0;
                if (gr < M) {
                    const float* ap = (const float*)A + (size_t)gr * lda + k0 + c8;
                    f0 = *(const float4*)ap;
                    f1 = *(const float4*)(ap + 4);
                }
                __hip_bfloat16* dstp = (__hip_bfloat16*)&As[r][c8];
                dstp[0] = __float2bfloat16(f0.x); dstp[1] = __float2bfloat16(f0.y);
                dstp[2] = __float2bfloat16(f0.z); dstp[3] = __float2bfloat16(f0.w);
                dstp[4] = __float2bfloat16(f1.x); dstp[5] = __float2bfloat16(f1.y);
                dstp[6] = __float2bfloat16(f1.z); dstp[7] = __float2bfloat16(f1.w);
            } else {
                uint4 val = make_uint4(0u, 0u, 0u, 0u);
                if (gr < M) val = *(const uint4*)((const ushort_t*)A + (size_t)gr * lda + k0 + c8);
                *(uint4*)(&As[r][c8]) = val;
            }
        }
#pragma unroll
        for (int i = 0; i < 2; ++i) {
            int v = t + i * 256;
            int r = v >> 2, c8 = (v & 3) * 8;
            *(uint4*)(&Bs[r][c8]) = *(const uint4*)(B + (size_t)(bn + r) * ldb + k0 + c8);
        }
        __syncthreads();

        bf16x8 af[4], bfr[4];
#pragma unroll
        for (int mi = 0; mi < 4; ++mi)
            af[mi] = *(const bf16x8*)(&As[wrow * 64 + mi * 16 + l16][qd * 8]);
#pragma unroll
        for (int ni = 0; ni < 4; ++ni)
            bfr[ni] = *(const bf16x8*)(&Bs[wcol * 64 + ni * 16 + l16][qd * 8]);
#pragma unroll
        for (int mi = 0; mi < 4; ++mi)
#pragma unroll
            for (int ni = 0; ni < 4; ++ni)
                acc[mi][ni] = __builtin_amdgcn_mfma_f32_16x16x32_bf16(
                    af[mi], bfr[ni], acc[mi][ni], 0, 0, 0);
        __syncthreads();
    }

#pragma unroll
    for (int mi = 0; mi < 4; ++mi) {
#pragma unroll
        for (int r = 0; r < 4; ++r) {
            int lrow = wrow * 64 + mi * 16 + qd * 4 + r;
            int grow = bm + lrow;
            if (grow >= M) continue;
#pragma unroll
            for (int ni = 0; ni < 4; ++ni) {
                int gc = bn + wcol * 64 + ni * 16 + l16;
                float v = acc[mi][ni][r] + bias[gc];
                if (ACT == 1) v = 0.5f * v * (1.f + erff(v * 0.70710678118654752f));
                size_t off = (size_t)(row0 + grow) * ldc + gc;
                if (OUTF32) ((float*)C)[off] = v;
                else ((__hip_bfloat16*)C)[off] = __float2bfloat16(v);
            }
        }
    }
}

// ---------------------------------------------------------------------------
__global__ __launch_bounds__(256) void attn_scores_kernel(
    const ushort_t* __restrict__ hb,
    const float* __restrict__ au_w, const float* __restrict__ au_b,
    const float* __restrict__ av_w,
    float* __restrict__ su, float* __restrict__ sv, int N)
{
    const int wave = threadIdx.x >> 6;
    const int lane = threadIdx.x & 63;
    const int n = blockIdx.x * 4 + wave;
    if (n >= N) return;

    const float h0 = __bfloat162float(((const __hip_bfloat16*)hb)[(size_t)n * DIM + lane]);
    const float h1 = __bfloat162float(((const __hip_bfloat16*)hb)[(size_t)n * DIM + 64 + lane]);

    float au[NH], av[NH];
#pragma unroll
    for (int hh = 0; hh < NH; ++hh) {
        au[hh] = h0 * au_w[hh * DIM + lane] + h1 * au_w[hh * DIM + 64 + lane];
        av[hh] = h0 * av_w[hh * DIM + lane] + h1 * av_w[hh * DIM + 64 + lane];
    }
#pragma unroll
    for (int off = 32; off >= 1; off >>= 1) {
#pragma unroll
        for (int hh = 0; hh < NH; ++hh) {
            au[hh] += __shfl_down(au[hh], off, 64);
            av[hh] += __shfl_down(av[hh], off, 64);
        }
    }
    if (lane == 0) {
#pragma unroll
        for (int hh = 0; hh < NH; ++hh) {
            su[(size_t)n * NH + hh] = au[hh] + au_b[hh];
            sv[(size_t)n * NH + hh] = av[hh];
        }
    }
}

// ---------------------------------------------------------------------------
// degree count + multi-block scan (kept from r10: analysis-clean; r9's
// single-block scan was 92.7 us of one-CU latency).
// ---------------------------------------------------------------------------
__global__ __launch_bounds__(256) void degree_count_kernel(
    const int* __restrict__ src, const int* __restrict__ dst,
    float* __restrict__ out_deg, int* __restrict__ in_cnt, int E)
{
    int e = blockIdx.x * 256 + threadIdx.x;
    if (e >= E) return;
    unsafeAtomicAdd(&out_deg[src[e]], 1.f);
    atomicAdd(&in_cnt[dst[e]], 1);
}

__global__ __launch_bounds__(256) void block_sum_kernel(
    const int* __restrict__ cnt, int* __restrict__ bsum)
{
    const int lane = threadIdx.x & 63, wid = threadIdx.x >> 6;
    int i = blockIdx.x * 256 + threadIdx.x;
    int v = (i < NNODES) ? cnt[i] : 0;
#pragma unroll
    for (int off = 32; off >= 1; off >>= 1) v += __shfl_down(v, off, 64);
    __shared__ int ws_[4];
    if (lane == 0) ws_[wid] = v;
    __syncthreads();
    if (threadIdx.x == 0) bsum[blockIdx.x] = ws_[0] + ws_[1] + ws_[2] + ws_[3];
}

__global__ __launch_bounds__(256) void block_scan_kernel(
    const int* __restrict__ bsum, int* __restrict__ boff)
{
    __shared__ int sb[256];
    const int t = threadIdx.x;
    int v = (t < NB) ? bsum[t] : 0;
    sb[t] = v;
    __syncthreads();
    for (int off = 1; off < 256; off <<= 1) {
        int u = (t >= off) ? sb[t - off] : 0;
        __syncthreads();
        sb[t] += u;
        __syncthreads();
    }
    if (t < NB) boff[t] = (t == 0) ? 0 : sb[t - 1];
}

__global__ __launch_bounds__(256) void final_scan_kernel(
    const int* __restrict__ cnt, const int* __restrict__ boff,
    int* __restrict__ rowstart)
{
    __shared__ int sb[256];
    const int t = threadIdx.x;
    const int b = blockIdx.x;
    int i = b * 256 + t;
    int v = (i < NNODES) ? cnt[i] : 0;
    sb[t] = v;
    __syncthreads();
    for (int off = 1; off < 256; off <<= 1) {
        int u = (t >= off) ? sb[t - off] : 0;
        __syncthreads();
        sb[t] += u;
        __syncthreads();
    }
    if (i < NNODES) rowstart[i] = boff[b] + sb[t] - v;   // exclusive
    if (b == 0 && t == 0) rowstart[NNODES] = NEDGES;
}

__global__ __launch_bounds__(256) void fill_csr_kernel(
    const int* __restrict__ src, const int* __restrict__ dst,
    const int* __restrict__ rowstart, int* __restrict__ cursor,
    int* __restrict__ esrc, int E)
{
    int e = blockIdx.x * 256 + threadIdx.x;
    if (e >= E) return;
    int d = dst[e];
    int pos = rowstart[d] + atomicAdd(&cursor[d], 1);
    esrc[pos] = src[e];
}

// ---------------------------------------------------------------------------
// Gather-aggregate v4 (r11): single-pass, latency-optimized.
// Old 2-pass version: MfmaUtil=0, VALUBusy=33%, HBM=23%, LDS-conflicts=0 ->
// latency-bound (VGPR=20 left ~1 edge in flight per wave). Changes:
//  * single pass: m = (sum ex*h) * (1/sum ex)  -> pass A, LDS cache and
//    __syncthreads deleted (LDS 9216 -> 0)
//  * lane owns dims {2*lane, 2*lane+1}: hb row = ONE coalesced uint load
//    (256B/wave/instr), su/sv as float2, cat writes as uint stores
//  * esrc preloaded into one reg per lane (deg<=64 here; guarded fallback),
//    distributed via __shfl -> esrc load off the dependent chain
//  * manual unroll-by-4 with load/compute phase split -> ~12 loads in flight
// Numerics identical up to fp32 rounding order (was absmax 0.0078).
// ---------------------------------------------------------------------------
__device__ __forceinline__ float bf_lo(uint_t v) {
    union { uint_t i; float f; } c; c.i = v << 16; return c.f;
}
__device__ __forceinline__ float bf_hi(uint_t v) {
    union { uint_t i; float f; } c; c.i = v & 0xffff0000u; return c.f;
}
__device__ __forceinline__ void st_bf2(ushort_t* p, float a, float b) {
    __hip_bfloat16 ba = __float2bfloat16(a), bb = __float2bfloat16(b);
    uint_t v = (uint_t)(*(ushort_t*)&ba) | ((uint_t)(*(ushort_t*)&bb) << 16);
    *(uint_t*)p = v;
}

__global__ __launch_bounds__(256) void gather_aggregate_kernel(
    const int* __restrict__ rowstart, const int* __restrict__ esrc,
    const ushort_t* __restrict__ hb,
    const float* __restrict__ su, const float* __restrict__ sv,
    const float* __restrict__ out_deg,
    ushort_t* __restrict__ cat, int N)
{
    const int wave = threadIdx.x >> 6;
    const int lane = threadIdx.x & 63;
    const int n = blockIdx.x * 4 + wave;
    if (n >= N) return;

    const int d0 = lane << 1;          // this lane's dims {d0, d0+1}
    const int h0 = d0 & 7;             // heads {h0, h0+1} (h0 even)

    const int e0  = rowstart[n];
    const int deg = rowstart[n + 1] - e0;
    const float2 svv = *(const float2*)(sv + (size_t)n * NH + h0);
    const float od_d = out_deg[n];

    // preload edge list into registers: lane i holds esrc[e0+i] (deg<=64 case)
    int es = 0;
    if (deg > 0) es = esrc[e0 + (lane < deg ? lane : deg - 1)];

    float den0 = 0.f, den1 = 0.f;
    float m0 = 0.f, m1 = 0.f, s0 = 0.f, s1 = 0.f, n0 = 0.f, n1 = 0.f;

    const int degm = deg & ~3;
    for (int j = 0; j < degm; j += 4) {
        int s4[4]; float2 su4[4]; float od4[4]; uint_t hv4[4];
#pragma unroll
        for (int u = 0; u < 4; ++u) {
            int jj = j + u;
            s4[u] = (jj < 64) ? __shfl(es, jj, 64) : esrc[e0 + jj];
        }
#pragma unroll
        for (int u = 0; u < 4; ++u) {
            su4[u] = *(const float2*)(su + (size_t)s4[u] * NH + h0);
            od4[u] = out_deg[s4[u]];
            hv4[u] = *(const uint_t*)(hb + (size_t)s4[u] * DIM + d0);
        }
#pragma unroll
        for (int u = 0; u < 4; ++u) {
            float sc0 = su4[u].x + svv.x; sc0 = sc0 < 0.f ? 0.2f * sc0 : sc0;
            float sc1 = su4[u].y + svv.y; sc1 = sc1 < 0.f ? 0.2f * sc1 : sc1;
            float ex0 = __expf(sc0), ex1 = __expf(sc1);
            den0 += ex0; den1 += ex1;
            float nrm = rsqrtf(od4[u] * od_d);
            float hs0 = bf_lo(hv4[u]), hs1 = bf_hi(hv4[u]);
            m0 += hs0 * ex0; m1 += hs1 * ex1;
            s0 += hs0;       s1 += hs1;
            n0 += hs0 * nrm; n1 += hs1 * nrm;
        }
    }
    for (int j = degm; j < deg; ++j) {
        int s = (j < 64) ? __shfl(es, j, 64) : esrc[e0 + j];
        float2 suv = *(const float2*)(su + (size_t)s * NH + h0);
        float odv  = out_deg[s];
        uint_t hv  = *(const uint_t*)(hb + (size_t)s * DIM + d0);
        float sc0 = suv.x + svv.x; sc0 = sc0 < 0.f ? 0.2f * sc0 : sc0;
        float sc1 = suv.y + svv.y; sc1 = sc1 < 0.f ? 0.2f * sc1 : sc1;
        float ex0 = __expf(sc0), ex1 = __expf(sc1);
        den0 += ex0; den1 += ex1;
        float nrm = rsqrtf(odv * od_d);
        float hs0 = bf_lo(hv), hs1 = bf_hi(hv);
        m0 += hs0 * ex0; m1 += hs1 * ex1;
        s0 += hs0;       s1 += hs1;
        n0 += hs0 * nrm; n1 += hs1 * nrm;
    }

    const float inv = 1.f / fmaxf((float)deg, 1.f);
    const float r0 = den0 > 0.f ? 1.f / den0 : 0.f;
    const float r1 = den1 > 0.f ? 1.f / den1 : 0.f;
    ushort_t* row = cat + (size_t)n * 512;
    *(uint_t*)(row + d0) = *(const uint_t*)(hb + (size_t)n * DIM + d0);
    st_bf2(row + 128 + d0, m0 * r0, m1 * r1);
    st_bf2(row + 256 + d0, s0 * inv, s1 * inv);
    st_bf2(row + 384 + d0, n0, n1);
}

// ---------------------------------------------------------------------------
extern "C" void kernel_launch(void* const* d_in, const int* in_sizes, int n_in,
                              void* d_out, int out_size, void* d_ws, size_t ws_size,
                              hipStream_t stream)
{
    const float* x    = (const float*)d_in[0];
    const int*   src  = (const int*)d_in[1];
    const int*   dst  = (const int*)d_in[2];
    const float* fc_w = (const float*)d_in[3];
    const float* fc_b = (const float*)d_in[4];
    const float* au_w = (const float*)d_in[5];
    const float* au_b = (const float*)d_in[6];
    const float* av_w = (const float*)d_in[7];
    const float* w1   = (const float*)d_in[8];
    const float* b1   = (const float*)d_in[9];
    const float* w2   = (const float*)d_in[10];
    const float* b2   = (const float*)d_in[11];
    float* out = (float*)d_out;

    const int N = NNODES, E = NEDGES;

    // ws layout (no trailing backslashes in comments -- r6 lesson)
    char* w = (char*)d_ws;
    ushort_t* fc_wb = (ushort_t*)w;  w += (size_t)DIM * DIM * 2;
    ushort_t* w1b   = (ushort_t*)w;  w += (size_t)HID * 512 * 2;
    ushort_t* w2b   = (ushort_t*)w;  w += (size_t)DIM * HID * 2;
    ushort_t* hb    = (ushort_t*)w;  w += (size_t)N * DIM * 2;       // 12.8 MB
    ushort_t* cat   = (ushort_t*)w;  w += (size_t)N * 512 * 2;       // 51.2 MB
    float* su       = (float*)w;     w += (size_t)N * NH * 4;
    float* sv       = (float*)w;     w += (size_t)N * NH * 4;
    float* out_deg  = (float*)w;     w += (size_t)N * 4;             // zeroed (1/3)
    int*   in_cnt   = (int*)w;       w += (size_t)N * 4;             // zeroed (2/3)
    int*   cursor   = (int*)w;       w += (size_t)N * 4;             // zeroed (3/3)
    int*   rowstart = (int*)w;       w += (size_t)(N + 16) * 4;
    int*   bsum     = (int*)w;       w += (size_t)256 * 4;
    int*   boff     = (int*)w;       w += (size_t)256 * 4;
    int*   esrc     = (int*)w;       w += (size_t)E * 4;             // 3.2 MB
    size_t base_bytes = (size_t)(w - (char*)d_ws);                   // ~72 MB
    ushort_t* fbuf  = (ushort_t*)w;

    const int CHR = (ws_size >= base_bytes + (size_t)N * 512 * 2 + 1024) ? N : 12500;

    (void)hipMemsetAsync(out_deg, 0, (size_t)N * 3 * 4, stream);

    convert_weights_kernel<<<1344, 256, 0, stream>>>(fc_w, w1, w2, fc_wb, w1b, w2b);

    // 1) h = x @ fc_w.T + fc_b  (AF32 staging converts x fp32->bf16 in-flight)
    {
        dim3 g(1, (N + 127) / 128);
        gemm_mfma<1, 0, 0><<<g, 256, 0, stream>>>(x, DIM, fc_wb, DIM, fc_b,
                                                  hb, DIM, 0, N, DIM);
    }
    // 2) su / sv
    attn_scores_kernel<<<(N + 3) / 4, 256, 0, stream>>>(hb, au_w, au_b, av_w, su, sv, N);
    // 3) degrees + CSR (multi-block scan)
    degree_count_kernel<<<(E + 255) / 256, 256, 0, stream>>>(src, dst, out_deg, in_cnt, E);
    block_sum_kernel<<<NB, 256, 0, stream>>>(in_cnt, bsum);
    block_scan_kernel<<<1, 256, 0, stream>>>(bsum, boff);
    final_scan_kernel<<<NB, 256, 0, stream>>>(in_cnt, boff, rowstart);
    fill_csr_kernel<<<(E + 255) / 256, 256, 0, stream>>>(src, dst, rowstart, cursor, esrc, E);
    // 4) gather aggregation -> full bf16 cat (no atomics, no LDS, single pass)
    gather_aggregate_kernel<<<(N + 3) / 4, 256, 0, stream>>>(
        rowstart, esrc, hb, su, sv, out_deg, cat, N);

    // 5) FFN: f = gelu(cat@w1.T+b1) -> out = f@w2.T+b2
    for (int c0 = 0; c0 < N; c0 += CHR) {
        int Mc = (c0 + CHR <= N) ? CHR : N - c0;
        {
            dim3 g(HID / 128, (Mc + 127) / 128);
            gemm_mfma<0, 0, 1><<<g, 256, 0, stream>>>(cat + (size_t)c0 * 512, 512,
                                                      w1b, 512, b1,
                                                      fbuf, HID, 0, Mc, 512);
        }
        {
            dim3 g(DIM / 128, (Mc + 127) / 128);
            gemm_mfma<0, 1, 0><<<g, 256, 0, stream>>>(fbuf, HID, w2b, HID, b2,
                                                      out, DIM, c0, Mc, 512);
        }
    }
}

// Round 2
// 425.502 us; speedup vs baseline: 1.1083x; 1.0330x over previous
//
#include <hip/hip_runtime.h>
#include <hip/hip_bf16.h>

#define NNODES 50000
#define NEDGES 800000
#define DIM 128
#define NH 8
#define HID 512
#define NB 196               // scan blocks: ceil(50000/256)

typedef unsigned short ushort_t;
typedef unsigned int uint_t;
typedef __attribute__((ext_vector_type(8))) short bf16x8;
typedef __attribute__((ext_vector_type(4))) float f32x4;

// ---------------------------------------------------------------------------
// all three weight matrices in one dispatch (16384 + 262144 + 65536 = 344064)
__global__ __launch_bounds__(256) void convert_weights_kernel(
    const float* __restrict__ fc_w, const float* __restrict__ w1,
    const float* __restrict__ w2,
    ushort_t* __restrict__ fc_wb, ushort_t* __restrict__ w1b,
    ushort_t* __restrict__ w2b)
{
    int i = blockIdx.x * 256 + threadIdx.x;
    if (i < 16384)
        ((__hip_bfloat16*)fc_wb)[i] = __float2bfloat16(fc_w[i]);
    else if (i < 278528)
        ((__hip_bfloat16*)w1b)[i - 16384] = __float2bfloat16(w1[i - 16384]);
    else if (i < 344064)
        ((__hip_bfloat16*)w2b)[i - 278528] = __float2bfloat16(w2[i - 278528]);
}

// ---------------------------------------------------------------------------
// MFMA NT GEMM v2 (r12): C = act(A@B^T + bias).
// r11 counters (FFN GEMM1): MfmaUtil=12%, VALUBusy=21%, HBM=23%, Occ=31%,
// bank-conflicts=6.4M -> latency/staging-bound pre-m97 structure.
// Changes (ladder step 3 / m193 +67% A/B):
//  * staging via __builtin_amdgcn_global_load_lds width=16 (bf16 A path + B
//    always): no VGPR round-trip, no ds_write, minimal staging VALU
//  * LDS linear [128][32] (DMA needs wave-base+lane*16 dest); bank conflicts
//    fixed by both-sides XOR swizzle (rule 21 / m173): 16B slot
//    q_phys = c_log ^ ((row>>1)&3); source address pre-swizzled, same XOR on
//    ds_read -> 2-way max (free, m136)
//  * AF32 path (fc GEMM): manual convert-staging for A kept (guarded), but
//    writes land at the swizzled slot; B still async
//  * LDS 20480->16384, launch_bounds (256,3)->(256,4) for more barrier overlap
// ---------------------------------------------------------------------------
template<int AF32, int OUTF32, int ACT>
__global__ __launch_bounds__(256, 4) void gemm_mfma(
    const void* A, int lda,
    const ushort_t* __restrict__ B, int ldb,
    const float* __restrict__ bias,
    void* C, int ldc, int row0,
    int M, int K)
{
    constexpr int BM = 128, BN = 128, BK = 32;
    __shared__ ushort_t As[BM * BK];     // linear, swizzled content, 8 KB
    __shared__ ushort_t Bs[BN * BK];     // 8 KB

    const int t    = threadIdx.x;
    const int bm   = blockIdx.y * BM;
    const int bn   = blockIdx.x * BN;
    const int wid  = t >> 6, lane = t & 63;
    const int wrow = wid >> 1, wcol = wid & 1;
    const int qd   = lane >> 4, l16 = lane & 15;

    f32x4 acc[4][4];
#pragma unroll
    for (int i = 0; i < 4; ++i)
#pragma unroll
        for (int j = 0; j < 4; ++j) acc[i][j] = (f32x4){0.f, 0.f, 0.f, 0.f};

    for (int k0 = 0; k0 < K; k0 += BK) {
        // stage: 512 slots of 16B per matrix; thread covers phys slots t, t+256.
        // phys slot v: row r = v>>2, phys colblk q = v&3; content = logical
        // colblk c = q ^ ((r>>1)&3)  (involution; ds_read applies same XOR)
#pragma unroll
        for (int it = 0; it < 2; ++it) {
            const int v = it * 256 + t;
            const int r = v >> 2, q = v & 3;
            const int c = q ^ ((r >> 1) & 3);
            // B tile: always async (rows bn+r always in-bounds: N dims 128/512)
            {
                const ushort_t* gB = B + (size_t)(bn + r) * ldb + k0 + c * 8;
                ushort_t* lB = &Bs[(it * 256 + wid * 64) * 8];   // wave-uniform
                __builtin_amdgcn_global_load_lds(
                    (const __attribute__((address_space(1))) uint_t*)gB,
                    (__attribute__((address_space(3))) uint_t*)lB, 16, 0, 0);
            }
            if (AF32) {
                int gr = bm + r;
                float4 f0 = make_float4(0.f, 0.f, 0.f, 0.f), f1 = f0;
                if (gr < M) {
                    const float* ap = (const float*)A + (size_t)gr * lda + k0 + c * 8;
                    f0 = *(const float4*)ap;
                    f1 = *(const float4*)(ap + 4);
                }
                __hip_bfloat16 tmp[8];
                tmp[0] = __float2bfloat16(f0.x); tmp[1] = __float2bfloat16(f0.y);
                tmp[2] = __float2bfloat16(f0.z); tmp[3] = __float2bfloat16(f0.w);
                tmp[4] = __float2bfloat16(f1.x); tmp[5] = __float2bfloat16(f1.y);
                tmp[6] = __float2bfloat16(f1.z); tmp[7] = __float2bfloat16(f1.w);
                *(uint4*)&As[(r * 4 + q) * 8] = *(const uint4*)tmp;
            } else {
                int gr = bm + r;
                if (gr >= M) gr = M - 1;   // clamp: safe dup-read, C-write guards
                const ushort_t* gA = (const ushort_t*)A + (size_t)gr * lda + k0 + c * 8;
                ushort_t* lA = &As[(it * 256 + wid * 64) * 8];   // wave-uniform
                __builtin_amdgcn_global_load_lds(
                    (const __attribute__((address_space(1))) uint_t*)gA,
                    (__attribute__((address_space(3))) uint_t*)lA, 16, 0, 0);
            }
        }
        __syncthreads();   // drains vmcnt (global_load_lds) + lgkmcnt

        bf16x8 af[4], bfr[4];
#pragma unroll
        for (int mi = 0; mi < 4; ++mi) {
            const int row = wrow * 64 + mi * 16 + l16;
            af[mi] = *(const bf16x8*)&As[row * BK + ((qd ^ ((row >> 1) & 3)) * 8)];
        }
#pragma unroll
        for (int ni = 0; ni < 4; ++ni) {
            const int row = wcol * 64 + ni * 16 + l16;
            bfr[ni] = *(const bf16x8*)&Bs[row * BK + ((qd ^ ((row >> 1) & 3)) * 8)];
        }
#pragma unroll
        for (int mi = 0; mi < 4; ++mi)
#pragma unroll
            for (int ni = 0; ni < 4; ++ni)
                acc[mi][ni] = __builtin_amdgcn_mfma_f32_16x16x32_bf16(
                    af[mi], bfr[ni], acc[mi][ni], 0, 0, 0);
        __syncthreads();
    }

#pragma unroll
    for (int mi = 0; mi < 4; ++mi) {
#pragma unroll
        for (int r = 0; r < 4; ++r) {
            int lrow = wrow * 64 + mi * 16 + qd * 4 + r;
            int grow = bm + lrow;
            if (grow >= M) continue;
#pragma unroll
            for (int ni = 0; ni < 4; ++ni) {
                int gc = bn + wcol * 64 + ni * 16 + l16;
                float v = acc[mi][ni][r] + bias[gc];
                if (ACT == 1) v = 0.5f * v * (1.f + erff(v * 0.70710678118654752f));
                size_t off = (size_t)(row0 + grow) * ldc + gc;
                if (OUTF32) ((float*)C)[off] = v;
                else ((__hip_bfloat16*)C)[off] = __float2bfloat16(v);
            }
        }
    }
}

// ---------------------------------------------------------------------------
__global__ __launch_bounds__(256) void attn_scores_kernel(
    const ushort_t* __restrict__ hb,
    const float* __restrict__ au_w, const float* __restrict__ au_b,
    const float* __restrict__ av_w,
    float* __restrict__ su, float* __restrict__ sv, int N)
{
    const int wave = threadIdx.x >> 6;
    const int lane = threadIdx.x & 63;
    const int n = blockIdx.x * 4 + wave;
    if (n >= N) return;

    const float h0 = __bfloat162float(((const __hip_bfloat16*)hb)[(size_t)n * DIM + lane]);
    const float h1 = __bfloat162float(((const __hip_bfloat16*)hb)[(size_t)n * DIM + 64 + lane]);

    float au[NH], av[NH];
#pragma unroll
    for (int hh = 0; hh < NH; ++hh) {
        au[hh] = h0 * au_w[hh * DIM + lane] + h1 * au_w[hh * DIM + 64 + lane];
        av[hh] = h0 * av_w[hh * DIM + lane] + h1 * av_w[hh * DIM + 64 + lane];
    }
#pragma unroll
    for (int off = 32; off >= 1; off >>= 1) {
#pragma unroll
        for (int hh = 0; hh < NH; ++hh) {
            au[hh] += __shfl_down(au[hh], off, 64);
            av[hh] += __shfl_down(av[hh], off, 64);
        }
    }
    if (lane == 0) {
#pragma unroll
        for (int hh = 0; hh < NH; ++hh) {
            su[(size_t)n * NH + hh] = au[hh] + au_b[hh];
            sv[(size_t)n * NH + hh] = av[hh];
        }
    }
}

// ---------------------------------------------------------------------------
// degree count + multi-block scan (kept from r10: analysis-clean; r9's
// single-block scan was 92.7 us of one-CU latency).
// ---------------------------------------------------------------------------
__global__ __launch_bounds__(256) void degree_count_kernel(
    const int* __restrict__ src, const int* __restrict__ dst,
    float* __restrict__ out_deg, int* __restrict__ in_cnt, int E)
{
    int e = blockIdx.x * 256 + threadIdx.x;
    if (e >= E) return;
    unsafeAtomicAdd(&out_deg[src[e]], 1.f);
    atomicAdd(&in_cnt[dst[e]], 1);
}

__global__ __launch_bounds__(256) void block_sum_kernel(
    const int* __restrict__ cnt, int* __restrict__ bsum)
{
    const int lane = threadIdx.x & 63, wid = threadIdx.x >> 6;
    int i = blockIdx.x * 256 + threadIdx.x;
    int v = (i < NNODES) ? cnt[i] : 0;
#pragma unroll
    for (int off = 32; off >= 1; off >>= 1) v += __shfl_down(v, off, 64);
    __shared__ int ws_[4];
    if (lane == 0) ws_[wid] = v;
    __syncthreads();
    if (threadIdx.x == 0) bsum[blockIdx.x] = ws_[0] + ws_[1] + ws_[2] + ws_[3];
}

__global__ __launch_bounds__(256) void block_scan_kernel(
    const int* __restrict__ bsum, int* __restrict__ boff)
{
    __shared__ int sb[256];
    const int t = threadIdx.x;
    int v = (t < NB) ? bsum[t] : 0;
    sb[t] = v;
    __syncthreads();
    for (int off = 1; off < 256; off <<= 1) {
        int u = (t >= off) ? sb[t - off] : 0;
        __syncthreads();
        sb[t] += u;
        __syncthreads();
    }
    if (t < NB) boff[t] = (t == 0) ? 0 : sb[t - 1];
}

__global__ __launch_bounds__(256) void final_scan_kernel(
    const int* __restrict__ cnt, const int* __restrict__ boff,
    int* __restrict__ rowstart)
{
    __shared__ int sb[256];
    const int t = threadIdx.x;
    const int b = blockIdx.x;
    int i = b * 256 + t;
    int v = (i < NNODES) ? cnt[i] : 0;
    sb[t] = v;
    __syncthreads();
    for (int off = 1; off < 256; off <<= 1) {
        int u = (t >= off) ? sb[t - off] : 0;
        __syncthreads();
        sb[t] += u;
        __syncthreads();
    }
    if (i < NNODES) rowstart[i] = boff[b] + sb[t] - v;   // exclusive
    if (b == 0 && t == 0) rowstart[NNODES] = NEDGES;
}

__global__ __launch_bounds__(256) void fill_csr_kernel(
    const int* __restrict__ src, const int* __restrict__ dst,
    const int* __restrict__ rowstart, int* __restrict__ cursor,
    int* __restrict__ esrc, int E)
{
    int e = blockIdx.x * 256 + threadIdx.x;
    if (e >= E) return;
    int d = dst[e];
    int pos = rowstart[d] + atomicAdd(&cursor[d], 1);
    esrc[pos] = src[e];
}

// ---------------------------------------------------------------------------
// Gather-aggregate v4 (r11, verified absmax 0.0078): single-pass,
// latency-optimized. Unchanged this round.
// ---------------------------------------------------------------------------
__device__ __forceinline__ float bf_lo(uint_t v) {
    union { uint_t i; float f; } c; c.i = v << 16; return c.f;
}
__device__ __forceinline__ float bf_hi(uint_t v) {
    union { uint_t i; float f; } c; c.i = v & 0xffff0000u; return c.f;
}
__device__ __forceinline__ void st_bf2(ushort_t* p, float a, float b) {
    __hip_bfloat16 ba = __float2bfloat16(a), bb = __float2bfloat16(b);
    uint_t v = (uint_t)(*(ushort_t*)&ba) | ((uint_t)(*(ushort_t*)&bb) << 16);
    *(uint_t*)p = v;
}

__global__ __launch_bounds__(256) void gather_aggregate_kernel(
    const int* __restrict__ rowstart, const int* __restrict__ esrc,
    const ushort_t* __restrict__ hb,
    const float* __restrict__ su, const float* __restrict__ sv,
    const float* __restrict__ out_deg,
    ushort_t* __restrict__ cat, int N)
{
    const int wave = threadIdx.x >> 6;
    const int lane = threadIdx.x & 63;
    const int n = blockIdx.x * 4 + wave;
    if (n >= N) return;

    const int d0 = lane << 1;          // this lane's dims {d0, d0+1}
    const int h0 = d0 & 7;             // heads {h0, h0+1} (h0 even)

    const int e0  = rowstart[n];
    const int deg = rowstart[n + 1] - e0;
    const float2 svv = *(const float2*)(sv + (size_t)n * NH + h0);
    const float od_d = out_deg[n];

    // preload edge list into registers: lane i holds esrc[e0+i] (deg<=64 case)
    int es = 0;
    if (deg > 0) es = esrc[e0 + (lane < deg ? lane : deg - 1)];

    float den0 = 0.f, den1 = 0.f;
    float m0 = 0.f, m1 = 0.f, s0 = 0.f, s1 = 0.f, n0 = 0.f, n1 = 0.f;

    const int degm = deg & ~3;
    for (int j = 0; j < degm; j += 4) {
        int s4[4]; float2 su4[4]; float od4[4]; uint_t hv4[4];
#pragma unroll
        for (int u = 0; u < 4; ++u) {
            int jj = j + u;
            s4[u] = (jj < 64) ? __shfl(es, jj, 64) : esrc[e0 + jj];
        }
#pragma unroll
        for (int u = 0; u < 4; ++u) {
            su4[u] = *(const float2*)(su + (size_t)s4[u] * NH + h0);
            od4[u] = out_deg[s4[u]];
            hv4[u] = *(const uint_t*)(hb + (size_t)s4[u] * DIM + d0);
        }
#pragma unroll
        for (int u = 0; u < 4; ++u) {
            float sc0 = su4[u].x + svv.x; sc0 = sc0 < 0.f ? 0.2f * sc0 : sc0;
            float sc1 = su4[u].y + svv.y; sc1 = sc1 < 0.f ? 0.2f * sc1 : sc1;
            float ex0 = __expf(sc0), ex1 = __expf(sc1);
            den0 += ex0; den1 += ex1;
            float nrm = rsqrtf(od4[u] * od_d);
            float hs0 = bf_lo(hv4[u]), hs1 = bf_hi(hv4[u]);
            m0 += hs0 * ex0; m1 += hs1 * ex1;
            s0 += hs0;       s1 += hs1;
            n0 += hs0 * nrm; n1 += hs1 * nrm;
        }
    }
    for (int j = degm; j < deg; ++j) {
        int s = (j < 64) ? __shfl(es, j, 64) : esrc[e0 + j];
        float2 suv = *(const float2*)(su + (size_t)s * NH + h0);
        float odv  = out_deg[s];
        uint_t hv  = *(const uint_t*)(hb + (size_t)s * DIM + d0);
        float sc0 = suv.x + svv.x; sc0 = sc0 < 0.f ? 0.2f * sc0 : sc0;
        float sc1 = suv.y + svv.y; sc1 = sc1 < 0.f ? 0.2f * sc1 : sc1;
        float ex0 = __expf(sc0), ex1 = __expf(sc1);
        den0 += ex0; den1 += ex1;
        float nrm = rsqrtf(odv * od_d);
        float hs0 = bf_lo(hv), hs1 = bf_hi(hv);
        m0 += hs0 * ex0; m1 += hs1 * ex1;
        s0 += hs0;       s1 += hs1;
        n0 += hs0 * nrm; n1 += hs1 * nrm;
    }

    const float inv = 1.f / fmaxf((float)deg, 1.f);
    const float r0 = den0 > 0.f ? 1.f / den0 : 0.f;
    const float r1 = den1 > 0.f ? 1.f / den1 : 0.f;
    ushort_t* row = cat + (size_t)n * 512;
    *(uint_t*)(row + d0) = *(const uint_t*)(hb + (size_t)n * DIM + d0);
    st_bf2(row + 128 + d0, m0 * r0, m1 * r1);
    st_bf2(row + 256 + d0, s0 * inv, s1 * inv);
    st_bf2(row + 384 + d0, n0, n1);
}

// ---------------------------------------------------------------------------
extern "C" void kernel_launch(void* const* d_in, const int* in_sizes, int n_in,
                              void* d_out, int out_size, void* d_ws, size_t ws_size,
                              hipStream_t stream)
{
    const float* x    = (const float*)d_in[0];
    const int*   src  = (const int*)d_in[1];
    const int*   dst  = (const int*)d_in[2];
    const float* fc_w = (const float*)d_in[3];
    const float* fc_b = (const float*)d_in[4];
    const float* au_w = (const float*)d_in[5];
    const float* au_b = (const float*)d_in[6];
    const float* av_w = (const float*)d_in[7];
    const float* w1   = (const float*)d_in[8];
    const float* b1   = (const float*)d_in[9];
    const float* w2   = (const float*)d_in[10];
    const float* b2   = (const float*)d_in[11];
    float* out = (float*)d_out;

    const int N = NNODES, E = NEDGES;

    // ws layout (no trailing backslashes in comments -- r6 lesson)
    char* w = (char*)d_ws;
    ushort_t* fc_wb = (ushort_t*)w;  w += (size_t)DIM * DIM * 2;
    ushort_t* w1b   = (ushort_t*)w;  w += (size_t)HID * 512 * 2;
    ushort_t* w2b   = (ushort_t*)w;  w += (size_t)DIM * HID * 2;
    ushort_t* hb    = (ushort_t*)w;  w += (size_t)N * DIM * 2;       // 12.8 MB
    ushort_t* cat   = (ushort_t*)w;  w += (size_t)N * 512 * 2;       // 51.2 MB
    float* su       = (float*)w;     w += (size_t)N * NH * 4;
    float* sv       = (float*)w;     w += (size_t)N * NH * 4;
    float* out_deg  = (float*)w;     w += (size_t)N * 4;             // zeroed (1/3)
    int*   in_cnt   = (int*)w;       w += (size_t)N * 4;             // zeroed (2/3)
    int*   cursor   = (int*)w;       w += (size_t)N * 4;             // zeroed (3/3)
    int*   rowstart = (int*)w;       w += (size_t)(N + 16) * 4;
    int*   bsum     = (int*)w;       w += (size_t)256 * 4;
    int*   boff     = (int*)w;       w += (size_t)256 * 4;
    int*   esrc     = (int*)w;       w += (size_t)E * 4;             // 3.2 MB
    size_t base_bytes = (size_t)(w - (char*)d_ws);                   // ~72 MB
    ushort_t* fbuf  = (ushort_t*)w;

    const int CHR = (ws_size >= base_bytes + (size_t)N * 512 * 2 + 1024) ? N : 12500;

    (void)hipMemsetAsync(out_deg, 0, (size_t)N * 3 * 4, stream);

    convert_weights_kernel<<<1344, 256, 0, stream>>>(fc_w, w1, w2, fc_wb, w1b, w2b);

    // 1) h = x @ fc_w.T + fc_b  (AF32 staging converts x fp32->bf16 in-flight)
    {
        dim3 g(1, (N + 127) / 128);
        gemm_mfma<1, 0, 0><<<g, 256, 0, stream>>>(x, DIM, fc_wb, DIM, fc_b,
                                                  hb, DIM, 0, N, DIM);
    }
    // 2) su / sv
    attn_scores_kernel<<<(N + 3) / 4, 256, 0, stream>>>(hb, au_w, au_b, av_w, su, sv, N);
    // 3) degrees + CSR (multi-block scan)
    degree_count_kernel<<<(E + 255) / 256, 256, 0, stream>>>(src, dst, out_deg, in_cnt, E);
    block_sum_kernel<<<NB, 256, 0, stream>>>(in_cnt, bsum);
    block_scan_kernel<<<1, 256, 0, stream>>>(bsum, boff);
    final_scan_kernel<<<NB, 256, 0, stream>>>(in_cnt, boff, rowstart);
    fill_csr_kernel<<<(E + 255) / 256, 256, 0, stream>>>(src, dst, rowstart, cursor, esrc, E);
    // 4) gather aggregation -> full bf16 cat (no atomics, no LDS, single pass)
    gather_aggregate_kernel<<<(N + 3) / 4, 256, 0, stream>>>(
        rowstart, esrc, hb, su, sv, out_deg, cat, N);

    // 5) FFN: f = gelu(cat@w1.T+b1) -> out = f@w2.T+b2
    for (int c0 = 0; c0 < N; c0 += CHR) {
        int Mc = (c0 + CHR <= N) ? CHR : N - c0;
        {
            dim3 g(HID / 128, (Mc + 127) / 128);
            gemm_mfma<0, 0, 1><<<g, 256, 0, stream>>>(cat + (size_t)c0 * 512, 512,
                                                      w1b, 512, b1,
                                                      fbuf, HID, 0, Mc, 512);
        }
        {
            dim3 g(DIM / 128, (Mc + 127) / 128);
            gemm_mfma<0, 1, 0><<<g, 256, 0, stream>>>(fbuf, HID, w2b, HID, b2,
                                                      out, DIM, c0, Mc, 512);
        }
    }
}